// Round 7
// baseline (952.887 us; speedup 1.0000x reference)
//
#include <hip/hip_runtime.h>
#include <hip/hip_bf16.h>

// ---------------------------------------------------------------------------
// GCN forward, round 7.
//   k_mfma: EXACT R4/R6 GEMM (128x128, BK=32, 4 waves 64x64, unit-XOR swizzle
//           on global source, linear LDS dest). Untouched this round.
//   k_agg_h: XCD-keyed column slicing — slice = blockIdx.x & 7 (round-robin
//           dispatch puts consecutive blocks on different XCDs), 8 slices x
//           64 cols. Per-XCD gather footprint 41MB -> 5.1MB (~L2-sized).
//           dword/lane loads (256B/wave/edge). Bit-identical numerics.
//   k_agg_out: layer-4 full-row gather + fused bias+softmax (unchanged).
// ---------------------------------------------------------------------------

#define THREADS 256

typedef __bf16 bf16_t;
typedef __bf16 bf16x8 __attribute__((ext_vector_type(8)));
typedef __bf16 bf16x4 __attribute__((ext_vector_type(4)));
typedef float  f32x4  __attribute__((ext_vector_type(4)));

typedef const __attribute__((address_space(1))) void* gas_ptr;
typedef __attribute__((address_space(3))) void*       las_ptr;

// ------------------------------ CSR build ----------------------------------

__global__ void k_zero_int(int* __restrict__ p, int n) {
    int i = blockIdx.x * blockDim.x + threadIdx.x;
    if (i < n) p[i] = 0;
}

__global__ void k_count(const int* __restrict__ dst, int* __restrict__ cnt, int E, int n) {
    int i = blockIdx.x * blockDim.x + threadIdx.x;
    if (i < E) {
        int d = dst[i];
        if ((unsigned)d < (unsigned)n) atomicAdd(&cnt[d], 1);
    }
}

__global__ void k_dinv(const int* __restrict__ cnt, float* __restrict__ dinv, int n) {
    int i = blockIdx.x * blockDim.x + threadIdx.x;
    if (i < n) dinv[i] = rsqrtf((float)(cnt[i] + 1));   // +1 self-loop
}

__global__ __launch_bounds__(1024) void k_scan(const int* __restrict__ cnt,
                                               int* __restrict__ row_ptr,
                                               int* __restrict__ cursor, int n)
{
    __shared__ int sm[1024];
    const int t = threadIdx.x;
    const int chunk = (n + 1023) >> 10;
    const int lo = t * chunk, hi = min(n, lo + chunk);
    int s = 0;
    for (int i = lo; i < hi; ++i) s += cnt[i];
    sm[t] = s;
    __syncthreads();
    for (int off = 1; off < 1024; off <<= 1) {
        int v = (t >= off) ? sm[t - off] : 0;
        __syncthreads();
        sm[t] += v;
        __syncthreads();
    }
    int run = sm[t] - s;
    for (int i = lo; i < hi; ++i) {
        row_ptr[i] = run;
        cursor[i]  = run;
        run += cnt[i];
    }
}

__global__ void k_fill(const int* __restrict__ src, const int* __restrict__ dst,
                       const float* __restrict__ dinv, int* __restrict__ cursor,
                       int2* __restrict__ ew, int E, int n)
{
    int i = blockIdx.x * blockDim.x + threadIdx.x;
    if (i < E) {
        int s = src[i], d = dst[i];
        if ((unsigned)s >= (unsigned)n || (unsigned)d >= (unsigned)n) return;
        int pos = atomicAdd(&cursor[d], 1);
        ew[pos] = make_int2(s, __float_as_int(dinv[s]));
    }
}

// --------------------------- f32 -> hi/lo bf16 -----------------------------

__global__ void k_split(const float* __restrict__ in, bf16_t* __restrict__ hi,
                        bf16_t* __restrict__ lo, int n4)
{
    int i = blockIdx.x * blockDim.x + threadIdx.x;
    const int stride = gridDim.x * blockDim.x;
    for (; i < n4; i += stride) {
        float4 v = ((const float4*)in)[i];
        bf16x4 h, l;
        h[0] = (bf16_t)v.x; l[0] = (bf16_t)(v.x - (float)h[0]);
        h[1] = (bf16_t)v.y; l[1] = (bf16_t)(v.y - (float)h[1]);
        h[2] = (bf16_t)v.z; l[2] = (bf16_t)(v.z - (float)h[2]);
        h[3] = (bf16_t)v.w; l[3] = (bf16_t)(v.w - (float)h[3]);
        ((bf16x4*)hi)[i] = h;
        ((bf16x4*)lo)[i] = l;
    }
}

// ------------------------ split-bf16 MFMA GEMM (R4) ------------------------
// C(MxN, f32) = (Ah+Al)(MxK) @ (Bh+Bl)(NxK)^T, dropping Al*Bl.
// Tile 128x128, BK=32, 256 threads = 4 waves (2m x 2n), 64x64 each.
// 2-row units of 8 16B-slots; slot = u ^ (unit&7), u = (row&1)*4 + kb.
// Inverse permutation on the GLOBAL source; LDS dest linear.
__global__ __launch_bounds__(256) void k_mfma(
    const bf16_t* __restrict__ Ah, const bf16_t* __restrict__ Al,
    const bf16_t* __restrict__ Bh, const bf16_t* __restrict__ Bl,
    float* __restrict__ C, int M, int N, int K)
{
    __shared__ bf16_t sAh[128 * 32];
    __shared__ bf16_t sAl[128 * 32];
    __shared__ bf16_t sBh[128 * 32];
    __shared__ bf16_t sBl[128 * 32];

    const int tid  = threadIdx.x;
    const int lane = tid & 63;
    const int wid  = tid >> 6;
    const int m0   = blockIdx.x * 128;
    const int n0   = blockIdx.y * 128;
    const int wm   = (wid >> 1) * 64;
    const int wn   = (wid & 1) * 64;

    f32x4 acc[4][4] = {};

    int asrc[2], bsrc[2], sdst[2];
#pragma unroll
    for (int i = 0; i < 2; ++i) {
        int p    = i * 256 + tid;
        int unit = p >> 3, sl = p & 7;
        int u    = sl ^ (unit & 7);
        int row  = (unit << 1) | (u >> 2);
        int kb   = u & 3;
        int gm   = m0 + row; if (gm >= M) gm = M - 1;   // clamp tail rows
        asrc[i]  = gm * K + kb * 8;
        bsrc[i]  = (n0 + row) * K + kb * 8;
        sdst[i]  = p * 8;                                // bf16 elems
    }

    for (int k0 = 0; k0 < K; k0 += 32) {
#pragma unroll
        for (int i = 0; i < 2; ++i) {
            __builtin_amdgcn_global_load_lds((gas_ptr)(Ah + asrc[i] + k0),
                                             (las_ptr)(sAh + sdst[i]), 16, 0, 0);
            __builtin_amdgcn_global_load_lds((gas_ptr)(Al + asrc[i] + k0),
                                             (las_ptr)(sAl + sdst[i]), 16, 0, 0);
            __builtin_amdgcn_global_load_lds((gas_ptr)(Bh + bsrc[i] + k0),
                                             (las_ptr)(sBh + sdst[i]), 16, 0, 0);
            __builtin_amdgcn_global_load_lds((gas_ptr)(Bl + bsrc[i] + k0),
                                             (las_ptr)(sBl + sdst[i]), 16, 0, 0);
        }
        __syncthreads();

        const int kb = lane >> 4;
        bf16x8 a_h[4], a_l[4], b_h[4], b_l[4];
#pragma unroll
        for (int mf = 0; mf < 4; ++mf) {
            int row  = wm + mf * 16 + (lane & 15);
            int unit = row >> 1;
            int sl   = (((row & 1) << 2) | kb) ^ (unit & 7);
            int off  = (unit * 8 + sl) * 8;
            a_h[mf] = *(const bf16x8*)(sAh + off);
            a_l[mf] = *(const bf16x8*)(sAl + off);
        }
#pragma unroll
        for (int nf = 0; nf < 4; ++nf) {
            int row  = wn + nf * 16 + (lane & 15);
            int unit = row >> 1;
            int sl   = (((row & 1) << 2) | kb) ^ (unit & 7);
            int off  = (unit * 8 + sl) * 8;
            b_h[nf] = *(const bf16x8*)(sBh + off);
            b_l[nf] = *(const bf16x8*)(sBl + off);
        }
#pragma unroll
        for (int mf = 0; mf < 4; ++mf)
#pragma unroll
            for (int nf = 0; nf < 4; ++nf) {
                acc[mf][nf] = __builtin_amdgcn_mfma_f32_16x16x32_bf16(
                    a_h[mf], b_h[nf], acc[mf][nf], 0, 0, 0);
                acc[mf][nf] = __builtin_amdgcn_mfma_f32_16x16x32_bf16(
                    a_l[mf], b_h[nf], acc[mf][nf], 0, 0, 0);
                acc[mf][nf] = __builtin_amdgcn_mfma_f32_16x16x32_bf16(
                    a_h[mf], b_l[nf], acc[mf][nf], 0, 0, 0);
            }
        __syncthreads();
    }

    // C/D layout: col = lane&15, row = (lane>>4)*4 + reg  [learn_hip m89/m91]
    const int cn = lane & 15;
    const int cr = (lane >> 4) * 4;
#pragma unroll
    for (int mf = 0; mf < 4; ++mf) {
#pragma unroll
        for (int r = 0; r < 4; ++r) {
            const int m = m0 + wm + mf * 16 + cr + r;
            if (m < M) {
                float* cp = C + (size_t)m * N + n0 + wn + cn;
                cp[0]  = acc[mf][0][r];
                cp[16] = acc[mf][1][r];
                cp[32] = acc[mf][2][r];
                cp[48] = acc[mf][3][r];
            }
        }
    }
}

// ----------------- hidden-layer gather, XCD-keyed column slice -------------
// slice = blockIdx.x & 7: with round-robin block->XCD dispatch, each XCD's
// resident blocks all gather from the SAME 64-col slice of Lin: per-XCD
// working set 20000*64*4B = 5.1 MB (~L2) instead of 41 MB. Lane l = column
// slice*64 + l (dword loads, 256B/wave/edge, coalesced). Numerics identical
// (per-column edge order unchanged).
__global__ __launch_bounds__(256) void k_agg_h(
    const float* __restrict__ Lin,
    bf16_t* __restrict__ OutH, bf16_t* __restrict__ OutL,
    const int* __restrict__ row_ptr, const int* __restrict__ cnt,
    const int2* __restrict__ ew, const float* __restrict__ dinv,
    const float* __restrict__ bias, int M)
{
    const int s   = blockIdx.x & 7;
    const int rg  = blockIdx.x >> 3;
    const int row = rg * 4 + (threadIdx.x >> 6);
    if (row >= M) return;
    const int lane = threadIdx.x & 63;
    const int colf = s * 64 + lane;          // float column index

    const float dr  = dinv[row];
    const int   beg = row_ptr[row];
    const int   num = cnt[row];

    float a = 0.f;
    for (int e = 0; e < num; ++e) {
        const int2 ee = ew[beg + e];
        a += __int_as_float(ee.y) * Lin[(size_t)ee.x * 512 + colf];
    }

    const float v  = Lin[(size_t)row * 512 + colf];
    const float o  = fmaxf(a * dr + dr * dr * v + bias[colf], 0.f);
    const bf16_t h = (bf16_t)o;
    const size_t eo = (size_t)row * 512 + colf;
    OutH[eo] = h;
    OutL[eo] = (bf16_t)(o - (float)h);
}

// ------------- layer-4 gather + fused bias + softmax (full row) ------------
__global__ __launch_bounds__(256) void k_agg_out(
    const float* __restrict__ Lin, float* __restrict__ OutF,
    const int* __restrict__ row_ptr, const int* __restrict__ cnt,
    const int2* __restrict__ ew, const float* __restrict__ dinv,
    const float* __restrict__ bias, int M)
{
    const int row = blockIdx.x * 4 + (threadIdx.x >> 6);
    if (row >= M) return;
    const int lane = threadIdx.x & 63;

    const float dr  = dinv[row];
    const int   beg = row_ptr[row];
    const int   num = cnt[row];

    float4 acc = make_float4(0.f, 0.f, 0.f, 0.f);
    for (int e = 0; e < num; ++e) {
        const int2 ee = ew[beg + e];
        const float w = __int_as_float(ee.y);
        const float4 v = ((const float4*)(Lin + (size_t)ee.x * 256))[lane];
        acc.x += w * v.x; acc.y += w * v.y;
        acc.z += w * v.z; acc.w += w * v.w;
    }

    const float4 v = ((const float4*)(Lin + (size_t)row * 256))[lane];
    const float4 b = ((const float4*)bias)[lane];
    const float dr2 = dr * dr;
    float4 o;
    o.x = acc.x * dr + dr2 * v.x + b.x;
    o.y = acc.y * dr + dr2 * v.y + b.y;
    o.z = acc.z * dr + dr2 * v.z + b.z;
    o.w = acc.w * dr + dr2 * v.w + b.w;
    float mx = fmaxf(fmaxf(o.x, o.y), fmaxf(o.z, o.w));
#pragma unroll
    for (int off = 32; off > 0; off >>= 1) mx = fmaxf(mx, __shfl_xor(mx, off));
    float e0 = expf(o.x - mx), e1 = expf(o.y - mx),
          e2 = expf(o.z - mx), e3 = expf(o.w - mx);
    float s = e0 + e1 + e2 + e3;
#pragma unroll
    for (int off = 32; off > 0; off >>= 1) s += __shfl_xor(s, off);
    const float inv = 1.0f / s;
    ((float4*)(OutF + (size_t)row * 256))[lane] =
        make_float4(e0 * inv, e1 * inv, e2 * inv, e3 * inv);
}

// ------------------------------- launcher ----------------------------------

extern "C" void kernel_launch(void* const* d_in, const int* in_sizes, int n_in,
                              void* d_out, int out_size, void* d_ws, size_t ws_size,
                              hipStream_t stream)
{
    const float* x    = (const float*)d_in[0];
    const int*   eidx = (const int*)d_in[1];      // int32 [2][E]
    const float* W1 = (const float*)d_in[2]; const float* b1 = (const float*)d_in[3];
    const float* W2 = (const float*)d_in[4]; const float* b2 = (const float*)d_in[5];
    const float* W3 = (const float*)d_in[6]; const float* b3 = (const float*)d_in[7];
    const float* W4 = (const float*)d_in[8]; const float* b4 = (const float*)d_in[9];

    const int M = in_sizes[0] / 512;     // 20000
    const int E = in_sizes[1] / 2;       // 320000
    const int DH = 512, DO = 256;

    const int* srcI = eidx;
    const int* dstI = eidx + E;

    // ---- workspace layout (bytes) ----
    char* ws = (char*)d_ws;
    int*    cnt     = (int*)   (ws + 0);                  // 80KB
    int*    row_ptr = (int*)   (ws + (1 << 17));
    int*    cursor  = (int*)   (ws + (2 << 17));
    float*  dinv    = (float*) (ws + (3 << 17));
    int2*   ew      = (int2*)  (ws + 655360);             // 2.56MB
    bf16_t* W1h = (bf16_t*)(ws + 4194304);
    bf16_t* W1l = (bf16_t*)(ws + 4718592);
    bf16_t* W2h = (bf16_t*)(ws + 5242880);
    bf16_t* W2l = (bf16_t*)(ws + 5767168);
    bf16_t* W3h = (bf16_t*)(ws + 6291456);
    bf16_t* W3l = (bf16_t*)(ws + 6815744);
    bf16_t* W4h = (bf16_t*)(ws + 7340032);
    bf16_t* W4l = (bf16_t*)(ws + 7602176);
    const size_t HALF = (size_t)20000 * 512 * 2;          // 20.48MB
    bf16_t* PH  = (bf16_t*)(ws + 7864320);                // activation pair (hi)
    bf16_t* PL  = (bf16_t*)(ws + 7864320 + HALF);         // activation pair (lo)
    float*  Lin = (float*) (ws + 7864320 + 2 * HALF);     // f32 GEMM out, 41MB
    float*  out = (float*)d_out;

    const int gN = (M + THREADS - 1) / THREADS;
    const int gE = (E + THREADS - 1) / THREADS;
    const dim3 gemmH((M + 127) / 128, DH / 128);
    const dim3 gemmO((M + 127) / 128, DO / 128);
    const int  gAggH = ((M + 3) / 4) * 8;                 // 8 XCD-keyed slices
    const int  gAggO = (M + 3) / 4;

    // ---- CSR build ----
    k_zero_int<<<gN, THREADS, 0, stream>>>(cnt, M);
    k_count   <<<gE, THREADS, 0, stream>>>(dstI, cnt, E, M);
    k_dinv    <<<gN, THREADS, 0, stream>>>(cnt, dinv, M);
    k_scan    <<<1, 1024, 0, stream>>>(cnt, row_ptr, cursor, M);
    k_fill    <<<gE, THREADS, 0, stream>>>(srcI, dstI, dinv, cursor, ew, E, M);

    // ---- operand splits ----
    k_split<<<2048, THREADS, 0, stream>>>(x,  PH,  PL,  M * DH / 4);
    k_split<<<256,  THREADS, 0, stream>>>(W1, W1h, W1l, DH * DH / 4);
    k_split<<<256,  THREADS, 0, stream>>>(W2, W2h, W2l, DH * DH / 4);
    k_split<<<256,  THREADS, 0, stream>>>(W3, W3h, W3l, DH * DH / 4);
    k_split<<<128,  THREADS, 0, stream>>>(W4, W4h, W4l, DO * DH / 4);

    // ---- Layer 1 ----
    k_mfma<<<gemmH, THREADS, 0, stream>>>(PH, PL, W1h, W1l, Lin, M, DH, 512);
    k_agg_h<<<gAggH, THREADS, 0, stream>>>(Lin, PH, PL, row_ptr, cnt, ew, dinv, b1, M);
    // ---- Layer 2 ----
    k_mfma<<<gemmH, THREADS, 0, stream>>>(PH, PL, W2h, W2l, Lin, M, DH, DH);
    k_agg_h<<<gAggH, THREADS, 0, stream>>>(Lin, PH, PL, row_ptr, cnt, ew, dinv, b2, M);
    // ---- Layer 3 ----
    k_mfma<<<gemmH, THREADS, 0, stream>>>(PH, PL, W3h, W3l, Lin, M, DH, DH);
    k_agg_h<<<gAggH, THREADS, 0, stream>>>(Lin, PH, PL, row_ptr, cnt, ew, dinv, b3, M);
    // ---- Layer 4 (fused bias+softmax in agg epilogue) ----
    k_mfma<<<gemmO, THREADS, 0, stream>>>(PH, PL, W4h, W4l, Lin, M, DO, DH);
    k_agg_out<<<gAggO, THREADS, 0, stream>>>(Lin, out, row_ptr, cnt, ew, dinv, b4, M);
}

// Round 8
// 572.341 us; speedup vs baseline: 1.6649x; 1.6649x over previous
//
#include <hip/hip_runtime.h>
#include <hip/hip_bf16.h>

// ---------------------------------------------------------------------------
// GCN forward, round 8.
//   k_mfma: R4 GEMM core (128x128, BK=32, 4 waves 64x64, unit-XOR swizzle on
//           global source, linear LDS dest) + XCD-bijective 1D grid remap
//           (m204): each XCD owns contiguous row-tile-major logical tiles so
//           a row-panel's 4 column-tiles hit the same L2 (A fetched once).
//   k_agg:  REVERTED to R3/R4 full-row gather (float4 x2 per lane, simple
//           edge loop, int2 metadata) — best measured operating point
//           (~100us). Fused bias+ReLU+split / bias+softmax epilogues.
// ---------------------------------------------------------------------------

#define THREADS 256

typedef __bf16 bf16_t;
typedef __bf16 bf16x8 __attribute__((ext_vector_type(8)));
typedef __bf16 bf16x4 __attribute__((ext_vector_type(4)));
typedef float  f32x4  __attribute__((ext_vector_type(4)));

typedef const __attribute__((address_space(1))) void* gas_ptr;
typedef __attribute__((address_space(3))) void*       las_ptr;

// ------------------------------ CSR build ----------------------------------

__global__ void k_zero_int(int* __restrict__ p, int n) {
    int i = blockIdx.x * blockDim.x + threadIdx.x;
    if (i < n) p[i] = 0;
}

__global__ void k_count(const int* __restrict__ dst, int* __restrict__ cnt, int E, int n) {
    int i = blockIdx.x * blockDim.x + threadIdx.x;
    if (i < E) {
        int d = dst[i];
        if ((unsigned)d < (unsigned)n) atomicAdd(&cnt[d], 1);
    }
}

__global__ void k_dinv(const int* __restrict__ cnt, float* __restrict__ dinv, int n) {
    int i = blockIdx.x * blockDim.x + threadIdx.x;
    if (i < n) dinv[i] = rsqrtf((float)(cnt[i] + 1));   // +1 self-loop
}

__global__ __launch_bounds__(1024) void k_scan(const int* __restrict__ cnt,
                                               int* __restrict__ row_ptr,
                                               int* __restrict__ cursor, int n)
{
    __shared__ int sm[1024];
    const int t = threadIdx.x;
    const int chunk = (n + 1023) >> 10;
    const int lo = t * chunk, hi = min(n, lo + chunk);
    int s = 0;
    for (int i = lo; i < hi; ++i) s += cnt[i];
    sm[t] = s;
    __syncthreads();
    for (int off = 1; off < 1024; off <<= 1) {
        int v = (t >= off) ? sm[t - off] : 0;
        __syncthreads();
        sm[t] += v;
        __syncthreads();
    }
    int run = sm[t] - s;
    for (int i = lo; i < hi; ++i) {
        row_ptr[i] = run;
        cursor[i]  = run;
        run += cnt[i];
    }
}

__global__ void k_fill(const int* __restrict__ src, const int* __restrict__ dst,
                       const float* __restrict__ dinv, int* __restrict__ cursor,
                       int2* __restrict__ ew, int E, int n)
{
    int i = blockIdx.x * blockDim.x + threadIdx.x;
    if (i < E) {
        int s = src[i], d = dst[i];
        if ((unsigned)s >= (unsigned)n || (unsigned)d >= (unsigned)n) return;
        int pos = atomicAdd(&cursor[d], 1);
        ew[pos] = make_int2(s, __float_as_int(dinv[s]));
    }
}

// --------------------------- f32 -> hi/lo bf16 -----------------------------

__global__ void k_split(const float* __restrict__ in, bf16_t* __restrict__ hi,
                        bf16_t* __restrict__ lo, int n4)
{
    int i = blockIdx.x * blockDim.x + threadIdx.x;
    const int stride = gridDim.x * blockDim.x;
    for (; i < n4; i += stride) {
        float4 v = ((const float4*)in)[i];
        bf16x4 h, l;
        h[0] = (bf16_t)v.x; l[0] = (bf16_t)(v.x - (float)h[0]);
        h[1] = (bf16_t)v.y; l[1] = (bf16_t)(v.y - (float)h[1]);
        h[2] = (bf16_t)v.z; l[2] = (bf16_t)(v.z - (float)h[2]);
        h[3] = (bf16_t)v.w; l[3] = (bf16_t)(v.w - (float)h[3]);
        ((bf16x4*)hi)[i] = h;
        ((bf16x4*)lo)[i] = l;
    }
}

// ------------------------ split-bf16 MFMA GEMM -----------------------------
// C(MxN, f32) = (Ah+Al)(MxK) @ (Bh+Bl)(NxK)^T, dropping Al*Bl.
// Tile 128x128, BK=32, 256 threads = 4 waves (2m x 2n), 64x64 each.
// 1D grid + XCD-bijective remap (m204): xcd = bid&7 owns a contiguous run of
// row-tile-major logical tiles -> the ntn column-tiles of one A row-panel
// land on the same XCD's L2 (A pair fetched once per panel, not ntn times).
__global__ __launch_bounds__(256) void k_mfma(
    const bf16_t* __restrict__ Ah, const bf16_t* __restrict__ Al,
    const bf16_t* __restrict__ Bh, const bf16_t* __restrict__ Bl,
    float* __restrict__ C, int M, int N, int K, int ntn)
{
    __shared__ bf16_t sAh[128 * 32];
    __shared__ bf16_t sAl[128 * 32];
    __shared__ bf16_t sBh[128 * 32];
    __shared__ bf16_t sBl[128 * 32];

    // --- XCD-bijective logical tile id (m204) ---
    const int nwg = gridDim.x;
    const int q   = nwg >> 3, r = nwg & 7;
    const int xcd = blockIdx.x & 7;
    const int idx = blockIdx.x >> 3;
    const int L   = (xcd < r ? xcd * (q + 1) : r * (q + 1) + (xcd - r) * q) + idx;
    const int rt  = L / ntn;           // row-tile (panel-major)
    const int ct  = L - rt * ntn;      // column-tile

    const int tid  = threadIdx.x;
    const int lane = tid & 63;
    const int wid  = tid >> 6;
    const int m0   = rt * 128;
    const int n0   = ct * 128;
    const int wm   = (wid >> 1) * 64;
    const int wn   = (wid & 1) * 64;

    f32x4 acc[4][4] = {};

    int asrc[2], bsrc[2], sdst[2];
#pragma unroll
    for (int i = 0; i < 2; ++i) {
        int p    = i * 256 + tid;
        int unit = p >> 3, sl = p & 7;
        int u    = sl ^ (unit & 7);
        int row  = (unit << 1) | (u >> 2);
        int kb   = u & 3;
        int gm   = m0 + row; if (gm >= M) gm = M - 1;   // clamp tail rows
        asrc[i]  = gm * K + kb * 8;
        bsrc[i]  = (n0 + row) * K + kb * 8;
        sdst[i]  = p * 8;                                // bf16 elems
    }

    for (int k0 = 0; k0 < K; k0 += 32) {
#pragma unroll
        for (int i = 0; i < 2; ++i) {
            __builtin_amdgcn_global_load_lds((gas_ptr)(Ah + asrc[i] + k0),
                                             (las_ptr)(sAh + sdst[i]), 16, 0, 0);
            __builtin_amdgcn_global_load_lds((gas_ptr)(Al + asrc[i] + k0),
                                             (las_ptr)(sAl + sdst[i]), 16, 0, 0);
            __builtin_amdgcn_global_load_lds((gas_ptr)(Bh + bsrc[i] + k0),
                                             (las_ptr)(sBh + sdst[i]), 16, 0, 0);
            __builtin_amdgcn_global_load_lds((gas_ptr)(Bl + bsrc[i] + k0),
                                             (las_ptr)(sBl + sdst[i]), 16, 0, 0);
        }
        __syncthreads();

        const int kb = lane >> 4;
        bf16x8 a_h[4], a_l[4], b_h[4], b_l[4];
#pragma unroll
        for (int mf = 0; mf < 4; ++mf) {
            int row  = wm + mf * 16 + (lane & 15);
            int unit = row >> 1;
            int sl   = (((row & 1) << 2) | kb) ^ (unit & 7);
            int off  = (unit * 8 + sl) * 8;
            a_h[mf] = *(const bf16x8*)(sAh + off);
            a_l[mf] = *(const bf16x8*)(sAl + off);
        }
#pragma unroll
        for (int nf = 0; nf < 4; ++nf) {
            int row  = wn + nf * 16 + (lane & 15);
            int unit = row >> 1;
            int sl   = (((row & 1) << 2) | kb) ^ (unit & 7);
            int off  = (unit * 8 + sl) * 8;
            b_h[nf] = *(const bf16x8*)(sBh + off);
            b_l[nf] = *(const bf16x8*)(sBl + off);
        }
#pragma unroll
        for (int mf = 0; mf < 4; ++mf)
#pragma unroll
            for (int nf = 0; nf < 4; ++nf) {
                acc[mf][nf] = __builtin_amdgcn_mfma_f32_16x16x32_bf16(
                    a_h[mf], b_h[nf], acc[mf][nf], 0, 0, 0);
                acc[mf][nf] = __builtin_amdgcn_mfma_f32_16x16x32_bf16(
                    a_l[mf], b_h[nf], acc[mf][nf], 0, 0, 0);
                acc[mf][nf] = __builtin_amdgcn_mfma_f32_16x16x32_bf16(
                    a_h[mf], b_l[nf], acc[mf][nf], 0, 0, 0);
            }
        __syncthreads();
    }

    // C/D layout: col = lane&15, row = (lane>>4)*4 + reg  [learn_hip m89/m91]
    const int cn = lane & 15;
    const int cr = (lane >> 4) * 4;
#pragma unroll
    for (int mf = 0; mf < 4; ++mf) {
#pragma unroll
        for (int r2 = 0; r2 < 4; ++r2) {
            const int m = m0 + wm + mf * 16 + cr + r2;
            if (m < M) {
                float* cp = C + (size_t)m * N + n0 + wn + cn;
                cp[0]  = acc[mf][0][r2];
                cp[16] = acc[mf][1][r2];
                cp[32] = acc[mf][2][r2];
                cp[48] = acc[mf][3][r2];
            }
        }
    }
}

// --------------------------- gather-aggregate ------------------------------
// Out[r] = dinv[r]*( sum_e w_e*Lin[col_e] ) + dinv[r]^2*Lin[r]
// Full-row per wave (NV4 float4 per lane), simple edge loop (R3 form).
// MODE 1: +bias, ReLU, write hi/lo bf16 pair. MODE 0: +bias, softmax, f32.
template <int NV4, int MODE>
__global__ __launch_bounds__(256) void k_agg(
    const float* __restrict__ Lin, float* __restrict__ OutF,
    bf16_t* __restrict__ OutH, bf16_t* __restrict__ OutL,
    const int* __restrict__ row_ptr, const int* __restrict__ cnt,
    const int2* __restrict__ ew, const float* __restrict__ dinv,
    const float* __restrict__ bias, int M)
{
    const int D = NV4 * 256;
    const int row = blockIdx.x * 4 + (threadIdx.x >> 6);
    if (row >= M) return;
    const int lane = threadIdx.x & 63;

    const float dr  = dinv[row];
    const int   beg = row_ptr[row];
    const int   num = cnt[row];

    float4 acc[NV4];
#pragma unroll
    for (int j = 0; j < NV4; ++j) acc[j] = make_float4(0.f, 0.f, 0.f, 0.f);

    for (int e = 0; e < num; ++e) {
        const int2 ee = ew[beg + e];
        const float w = __int_as_float(ee.y);
        const float4* p = (const float4*)(Lin + (size_t)ee.x * D) + lane;
#pragma unroll
        for (int j = 0; j < NV4; ++j) {
            float4 v = p[j * 64];
            acc[j].x += w * v.x; acc[j].y += w * v.y;
            acc[j].z += w * v.z; acc[j].w += w * v.w;
        }
    }

    const float4* ps = (const float4*)(Lin + (size_t)row * D) + lane;
    const float dr2 = dr * dr;

    if (MODE == 1) {
#pragma unroll
        for (int j = 0; j < NV4; ++j) {
            float4 v = ps[j * 64];
            const float4 b = ((const float4*)bias)[j * 64 + lane];
            float4 o;
            o.x = fmaxf(acc[j].x * dr + dr2 * v.x + b.x, 0.f);
            o.y = fmaxf(acc[j].y * dr + dr2 * v.y + b.y, 0.f);
            o.z = fmaxf(acc[j].z * dr + dr2 * v.z + b.z, 0.f);
            o.w = fmaxf(acc[j].w * dr + dr2 * v.w + b.w, 0.f);
            bf16x4 h, l;
            h[0] = (bf16_t)o.x; l[0] = (bf16_t)(o.x - (float)h[0]);
            h[1] = (bf16_t)o.y; l[1] = (bf16_t)(o.y - (float)h[1]);
            h[2] = (bf16_t)o.z; l[2] = (bf16_t)(o.z - (float)h[2]);
            h[3] = (bf16_t)o.w; l[3] = (bf16_t)(o.w - (float)h[3]);
            const size_t eo = (size_t)row * D + lane * 4 + j * 256;
            *(bf16x4*)(OutH + eo) = h;
            *(bf16x4*)(OutL + eo) = l;
        }
    } else {
        float4 v = ps[0];
        const float4 b = ((const float4*)bias)[lane];
        float4 o;
        o.x = acc[0].x * dr + dr2 * v.x + b.x;
        o.y = acc[0].y * dr + dr2 * v.y + b.y;
        o.z = acc[0].z * dr + dr2 * v.z + b.z;
        o.w = acc[0].w * dr + dr2 * v.w + b.w;
        float mx = fmaxf(fmaxf(o.x, o.y), fmaxf(o.z, o.w));
#pragma unroll
        for (int off = 32; off > 0; off >>= 1) mx = fmaxf(mx, __shfl_xor(mx, off));
        float e0 = expf(o.x - mx), e1 = expf(o.y - mx),
              e2 = expf(o.z - mx), e3 = expf(o.w - mx);
        float s = e0 + e1 + e2 + e3;
#pragma unroll
        for (int off = 32; off > 0; off >>= 1) s += __shfl_xor(s, off);
        const float inv = 1.0f / s;
        ((float4*)(OutF + (size_t)row * D))[lane] =
            make_float4(e0 * inv, e1 * inv, e2 * inv, e3 * inv);
    }
}

// ------------------------------- launcher ----------------------------------

extern "C" void kernel_launch(void* const* d_in, const int* in_sizes, int n_in,
                              void* d_out, int out_size, void* d_ws, size_t ws_size,
                              hipStream_t stream)
{
    const float* x    = (const float*)d_in[0];
    const int*   eidx = (const int*)d_in[1];      // int32 [2][E]
    const float* W1 = (const float*)d_in[2]; const float* b1 = (const float*)d_in[3];
    const float* W2 = (const float*)d_in[4]; const float* b2 = (const float*)d_in[5];
    const float* W3 = (const float*)d_in[6]; const float* b3 = (const float*)d_in[7];
    const float* W4 = (const float*)d_in[8]; const float* b4 = (const float*)d_in[9];

    const int M = in_sizes[0] / 512;     // 20000
    const int E = in_sizes[1] / 2;       // 320000
    const int DH = 512, DO = 256;

    const int* srcI = eidx;
    const int* dstI = eidx + E;

    // ---- workspace layout (bytes) ----
    char* ws = (char*)d_ws;
    int*    cnt     = (int*)   (ws + 0);                  // 80KB
    int*    row_ptr = (int*)   (ws + (1 << 17));
    int*    cursor  = (int*)   (ws + (2 << 17));
    float*  dinv    = (float*) (ws + (3 << 17));
    int2*   ew      = (int2*)  (ws + 655360);             // 2.56MB
    bf16_t* W1h = (bf16_t*)(ws + 4194304);
    bf16_t* W1l = (bf16_t*)(ws + 4718592);
    bf16_t* W2h = (bf16_t*)(ws + 5242880);
    bf16_t* W2l = (bf16_t*)(ws + 5767168);
    bf16_t* W3h = (bf16_t*)(ws + 6291456);
    bf16_t* W3l = (bf16_t*)(ws + 6815744);
    bf16_t* W4h = (bf16_t*)(ws + 7340032);
    bf16_t* W4l = (bf16_t*)(ws + 7602176);
    const size_t HALF = (size_t)20000 * 512 * 2;          // 20.48MB
    bf16_t* PH  = (bf16_t*)(ws + 7864320);                // activation pair (hi)
    bf16_t* PL  = (bf16_t*)(ws + 7864320 + HALF);         // activation pair (lo)
    float*  Lin = (float*) (ws + 7864320 + 2 * HALF);     // f32 GEMM out, 41MB
    float*  out = (float*)d_out;

    const int gN = (M + THREADS - 1) / THREADS;
    const int gE = (E + THREADS - 1) / THREADS;
    const int nRT   = (M + 127) / 128;                    // 157 row tiles
    const int gemmH = nRT * (DH / 128);                   // 628 (1D, remapped)
    const int gemmO = nRT * (DO / 128);                   // 314
    const int gAgg  = (M + 3) / 4;

    // ---- CSR build ----
    k_zero_int<<<gN, THREADS, 0, stream>>>(cnt, M);
    k_count   <<<gE, THREADS, 0, stream>>>(dstI, cnt, E, M);
    k_dinv    <<<gN, THREADS, 0, stream>>>(cnt, dinv, M);
    k_scan    <<<1, 1024, 0, stream>>>(cnt, row_ptr, cursor, M);
    k_fill    <<<gE, THREADS, 0, stream>>>(srcI, dstI, dinv, cursor, ew, E, M);

    // ---- operand splits ----
    k_split<<<2048, THREADS, 0, stream>>>(x,  PH,  PL,  M * DH / 4);
    k_split<<<256,  THREADS, 0, stream>>>(W1, W1h, W1l, DH * DH / 4);
    k_split<<<256,  THREADS, 0, stream>>>(W2, W2h, W2l, DH * DH / 4);
    k_split<<<256,  THREADS, 0, stream>>>(W3, W3h, W3l, DH * DH / 4);
    k_split<<<128,  THREADS, 0, stream>>>(W4, W4h, W4l, DO * DH / 4);

    // ---- Layer 1 ----
    k_mfma<<<gemmH, THREADS, 0, stream>>>(PH, PL, W1h, W1l, Lin, M, DH, 512, DH / 128);
    k_agg<2, 1><<<gAgg, THREADS, 0, stream>>>(Lin, nullptr, PH, PL, row_ptr, cnt, ew, dinv, b1, M);
    // ---- Layer 2 ----
    k_mfma<<<gemmH, THREADS, 0, stream>>>(PH, PL, W2h, W2l, Lin, M, DH, DH, DH / 128);
    k_agg<2, 1><<<gAgg, THREADS, 0, stream>>>(Lin, nullptr, PH, PL, row_ptr, cnt, ew, dinv, b2, M);
    // ---- Layer 3 ----
    k_mfma<<<gemmH, THREADS, 0, stream>>>(PH, PL, W3h, W3l, Lin, M, DH, DH, DH / 128);
    k_agg<2, 1><<<gAgg, THREADS, 0, stream>>>(Lin, nullptr, PH, PL, row_ptr, cnt, ew, dinv, b3, M);
    // ---- Layer 4 (fused bias+softmax in agg epilogue) ----
    k_mfma<<<gemmO, THREADS, 0, stream>>>(PH, PL, W4h, W4l, Lin, M, DO, DH, DO / 128);
    k_agg<1, 0><<<gAgg, THREADS, 0, stream>>>(Lin, out, nullptr, nullptr, row_ptr, cnt, ew, dinv, b4, M);
}